// Round 1
// 287.859 us; speedup vs baseline: 1.0614x; 1.0614x over previous
//
#include <hip/hip_runtime.h>
#include <hip/hip_bf16.h>
#include <math.h>

#define B_ 16
#define N_ 1024
#define C_ 256

typedef unsigned short ushort_t;
typedef __attribute__((ext_vector_type(8))) short short8;   // 8 bf16 = 4 VGPRs
typedef __attribute__((ext_vector_type(4))) float f32x4;

static __device__ __forceinline__ ushort_t f2bf(float f) {
    __hip_bfloat16 h = __float2bfloat16(f);
    return *(ushort_t*)&h;
}

static __device__ __forceinline__ float bf2f(ushort_t u) {
    return __uint_as_float(((unsigned int)u) << 16);
}

// async global->LDS, 16B per lane; lds base must be wave-uniform (HW adds lane*16)
static __device__ __forceinline__ void async16(const ushort_t* g, ushort_t* l) {
    __builtin_amdgcn_global_load_lds(
        (const __attribute__((address_space(1))) unsigned int*)g,
        (__attribute__((address_space(3))) unsigned int*)l,
        16, 0, 0);
}

// ---------------------------------------------------------------------------
// C[M,N] = alpha * A[M,K] @ B[N,K]^T   (A,B bf16 row-major; C fp32 or bf16)
// 128x128 tile, BK=32, 4 waves (2x2), 16x16x32 MFMA, 4x4 tiles/wave.
// T3-min 2-phase: double-buffered LDS, next tile staged BEFORE current tile's
// ds_read+MFMA, ONE barrier per K-step (implicit vmcnt(0) at the barrier
// covers the in-flight global_load_lds; loads fly under the MFMA phase).
// K-loop LDS XOR-swizzled (<=2-way, free). Epilogue stages acc tiles through
// the first 16KB of LDS and emits fully-coalesced float4 / short8 stores.
// All dims multiples of 128/32 -> no bounds checks.
// ---------------------------------------------------------------------------
template <int OUT_BF16>
__global__ __launch_bounds__(256) void gemm_nt_bf16(
    const ushort_t* __restrict__ A, const ushort_t* __restrict__ B,
    void* __restrict__ Cp, int M, int N, int K,
    long sA, long sB, long sC, float alpha)
{
    A += (long)blockIdx.z * sA;
    B += (long)blockIdx.z * sB;

    __shared__ ushort_t sh[2][2 * 128 * 32];   // double-buffered As|Bs (32 KB)
    float* shF = (float*)sh;                    // epilogue reuses first 16 KB

    const int tid  = threadIdx.x;
    const int wave = tid >> 6;          // 0..3
    const int lane = tid & 63;
    const int wm   = wave >> 1;         // row half of 128
    const int wn   = wave & 1;          // col half of 128
    const int row0 = blockIdx.y * 128;
    const int col0 = blockIdx.x * 128;

    // ---- staging addresses (per wave: 2 groups of 16 rows for A, 2 for B)
    const int r_grp = lane >> 2;        // 0..15 row within group
    const int c_chk = lane & 3;         // 0..3  16B chunk within 64B row
    const int swz   = c_chk ^ ((r_grp >> 1) & 3);   // swizzled source chunk
    const int ga0 = wave * 2, ga1 = wave * 2 + 1;

    const ushort_t* agp0 = A + (long)(row0 + ga0 * 16 + r_grp) * K + swz * 8;
    const ushort_t* agp1 = A + (long)(row0 + ga1 * 16 + r_grp) * K + swz * 8;
    const ushort_t* bgp0 = B + (long)(col0 + ga0 * 16 + r_grp) * K + swz * 8;
    const ushort_t* bgp1 = B + (long)(col0 + ga1 * 16 + r_grp) * K + swz * 8;

    // ---- fragment read addressing
    const int lr16 = lane & 15;
    const int q16  = lane >> 4;                       // 0..3
    const int slot = (q16 ^ ((lr16 >> 1) & 3)) * 8;   // swizzled read slot

    f32x4 acc[4][4] = {};

    // prologue: stage k=0 into buffer 0
    {
        ushort_t* As = sh[0];
        ushort_t* Bs = sh[0] + 128 * 32;
        async16(agp0, &As[ga0 * 512]);
        async16(agp1, &As[ga1 * 512]);
        async16(bgp0, &Bs[ga0 * 512]);
        async16(bgp1, &Bs[ga1 * 512]);
    }
    __syncthreads();   // drains vmcnt -> buf0 ready

    int p = 0;
    for (int k0 = 0; k0 < K; k0 += 32) {
        // issue next-tile stage first: overlaps with ds_read + MFMA below
        if (k0 + 32 < K) {
            ushort_t* As = sh[p ^ 1];
            ushort_t* Bs = sh[p ^ 1] + 128 * 32;
            async16(agp0 + k0 + 32, &As[ga0 * 512]);
            async16(agp1 + k0 + 32, &As[ga1 * 512]);
            async16(bgp0 + k0 + 32, &Bs[ga0 * 512]);
            async16(bgp1 + k0 + 32, &Bs[ga1 * 512]);
        }

        const ushort_t* As = sh[p];
        const ushort_t* Bs = sh[p] + 128 * 32;
        short8 av[4], bv[4];
#pragma unroll
        for (int i = 0; i < 4; i++)
            av[i] = *(const short8*)&As[(wm * 64 + i * 16 + lr16) * 32 + slot];
#pragma unroll
        for (int j = 0; j < 4; j++)
            bv[j] = *(const short8*)&Bs[(wn * 64 + j * 16 + lr16) * 32 + slot];

#pragma unroll
        for (int i = 0; i < 4; i++)
#pragma unroll
            for (int j = 0; j < 4; j++)
                acc[i][j] = __builtin_amdgcn_mfma_f32_16x16x32_bf16(
                    av[i], bv[j], acc[i][j], 0, 0, 0);

        __syncthreads();   // next buf staged + this buf free for re-stage
        p ^= 1;
    }

    // ---- epilogue via LDS: 4 passes of 32 rows x 128 cols fp32 (16 KB)
    // acc C/D layout: col=lane&15, row=q16*4+reg
#pragma unroll
    for (int i = 0; i < 4; i++) {
#pragma unroll
        for (int j = 0; j < 4; j++) {
            const int rl = wm * 16 + q16 * 4;         // +r below
            const int cl = wn * 64 + j * 16 + lr16;
#pragma unroll
            for (int r = 0; r < 4; r++) {
                const int rr = rl + r;
                const int xr = ((rr >> 2) & 1) << 4;  // split quads across bank halves
                shF[rr * 128 + (cl ^ xr)] = alpha * acc[i][j][r];
            }
        }
        __syncthreads();

        if constexpr (OUT_BF16) {
            ushort_t* C = (ushort_t*)Cp + (long)blockIdx.z * sC;
#pragma unroll
            for (int v = 0; v < 2; v++) {
                const int idx = v * 256 + tid;        // 0..511 short8-chunks
                const int rl = idx >> 4;              // 32 rows
                const int c8 = idx & 15;              // 16 chunks of 8 elems
                const int xr4 = ((rl >> 2) & 1) << 2; // float4-index XOR
                const int gr = row0 + (rl >> 4) * 64 + i * 16 + (rl & 15);
                const float4 a = ((const float4*)(shF + rl * 128))[(c8 * 2) ^ xr4];
                const float4 b = ((const float4*)(shF + rl * 128))[(c8 * 2 + 1) ^ xr4];
                short8 pk;
                pk[0] = (short)f2bf(a.x); pk[1] = (short)f2bf(a.y);
                pk[2] = (short)f2bf(a.z); pk[3] = (short)f2bf(a.w);
                pk[4] = (short)f2bf(b.x); pk[5] = (short)f2bf(b.y);
                pk[6] = (short)f2bf(b.z); pk[7] = (short)f2bf(b.w);
                *(short8*)(C + (long)gr * N + col0 + c8 * 8) = pk;
            }
        } else {
            float* C = (float*)Cp + (long)blockIdx.z * sC;
#pragma unroll
            for (int v = 0; v < 4; v++) {
                const int idx = v * 256 + tid;        // 0..1023 float4-chunks
                const int rl = idx >> 5;              // 32 rows
                const int c4 = idx & 31;
                const int xr4 = ((rl >> 2) & 1) << 2;
                const int gr = row0 + (rl >> 4) * 64 + i * 16 + (rl & 15);
                const float4 val = ((const float4*)(shF + rl * 128))[c4 ^ xr4];
                *(float4*)(C + (long)gr * N + col0 + c4 * 4) = val;
            }
        }
        __syncthreads();
    }
}

// ---------------------------------------------------------------------------
// Fused cast kernel, one launch:
//   blocks [0,4096): x fp32 -> bf16 (x4 vectorized) + per-row sigma = x . Wsig
//                    (one wave = one row; shuffle reduce; |sigma| -> asig)
//   blocks [4096,4288): W[256,256] fp32 (q/k/v) -> WbfT bf16 transposed
// ---------------------------------------------------------------------------
__global__ __launch_bounds__(256) void cast_fused(
    const float* __restrict__ x, ushort_t* __restrict__ xbf,
    const float* __restrict__ Wq, const float* __restrict__ Wk,
    const float* __restrict__ Wv, ushort_t* __restrict__ WbfT,
    const float* __restrict__ Wsig, float* __restrict__ asig)
{
    __shared__ float t[32][33];
    const int blk = blockIdx.x;
    if (blk < 4096) {
        const long i = ((long)blk * 256 + threadIdx.x) * 4;
        const float4 v = *(const float4*)(x + i);
        ushort4 o;
        o.x = f2bf(v.x); o.y = f2bf(v.y); o.z = f2bf(v.z); o.w = f2bf(v.w);
        *(ushort4*)(xbf + i) = o;
        if (asig) {
            const int lane = threadIdx.x & 63;
            const float4 w = *(const float4*)(Wsig + lane * 4);
            float d = v.x * w.x + v.y * w.y + v.z * w.z + v.w * w.w;
#pragma unroll
            for (int off = 32; off; off >>= 1) d += __shfl_down(d, off, 64);
            if (lane == 0) asig[blk * 4 + (threadIdx.x >> 6)] = fabsf(d);
        }
    } else {
        const int m = blk - 4096;                 // 0..191
        const float* W = ((m >> 6) == 0) ? Wq : ((m >> 6) == 1) ? Wk : Wv;
        const int rem = m & 63;
        const int n0 = (rem & 7) * 32, k0 = (rem >> 3) * 32;
        const int tx = threadIdx.x & 31, ty = threadIdx.x >> 5;   // (32,8)
#pragma unroll
        for (int j = 0; j < 4; j++)
            t[ty + j * 8][tx] = W[(long)(k0 + ty + j * 8) * 256 + n0 + tx];
        __syncthreads();
        ushort_t* o = WbfT + (long)(m >> 6) * 65536;
#pragma unroll
        for (int j = 0; j < 4; j++)
            o[(long)(n0 + ty + j * 8) * 256 + k0 + tx] = f2bf(t[tx][ty + j * 8]);
    }
}

// ---------------------------------------------------------------------------
// Vbf[b][1024,256] -> VbfT[b][256,1024] (bf16 LDS tile transpose)
// ---------------------------------------------------------------------------
__global__ __launch_bounds__(256) void transpose_v_kernel(
    const ushort_t* __restrict__ V, ushort_t* __restrict__ VT)
{
    __shared__ ushort_t t[32][33];
    const long NC = (long)N_ * C_;
    const ushort_t* Vb = V + (long)blockIdx.z * NC;
    ushort_t* Tb = VT + (long)blockIdx.z * NC;
    const int n0 = blockIdx.x * 32, m0 = blockIdx.y * 32;
    const int tx = threadIdx.x & 31, ty = threadIdx.x >> 5;
#pragma unroll
    for (int j = 0; j < 4; j++)
        t[ty + j * 8][tx] = Vb[(long)(m0 + ty + j * 8) * C_ + n0 + tx];
    __syncthreads();
#pragma unroll
    for (int j = 0; j < 4; j++)
        Tb[(long)(n0 + ty + j * 8) * N_ + m0 + tx] = t[tx][ty + j * 8];
}

// ---------------------------------------------------------------------------
// Softmax over batch axis (16 slices, stride N*N), 4 cells per thread.
// Reads bf16 raw scores, writes fp32 S (final output) + normalized bf16 back
// IN PLACE over the raw scores (each cell read+written by the same thread).
// ---------------------------------------------------------------------------
__global__ __launch_bounds__(256) void softmax_batch(
    ushort_t* __restrict__ Sc, float* __restrict__ S)
{
    const long NN = (long)N_ * N_;
    const long i4 = ((long)blockIdx.x * 256 + threadIdx.x) * 4;

    float4 v[B_];
    float mx = -INFINITY, my = -INFINITY, mz = -INFINITY, mw = -INFINITY;
#pragma unroll
    for (int b = 0; b < B_; b++) {
        const ushort4 u = *(const ushort4*)(Sc + (long)b * NN + i4);
        v[b].x = bf2f(u.x); v[b].y = bf2f(u.y);
        v[b].z = bf2f(u.z); v[b].w = bf2f(u.w);
        mx = fmaxf(mx, v[b].x); my = fmaxf(my, v[b].y);
        mz = fmaxf(mz, v[b].z); mw = fmaxf(mw, v[b].w);
    }
    float sx = 0.f, sy = 0.f, sz = 0.f, sw = 0.f;
#pragma unroll
    for (int b = 0; b < B_; b++) {
        v[b].x = __expf(v[b].x - mx); sx += v[b].x;
        v[b].y = __expf(v[b].y - my); sy += v[b].y;
        v[b].z = __expf(v[b].z - mz); sz += v[b].z;
        v[b].w = __expf(v[b].w - mw); sw += v[b].w;
    }
    const float ix = 1.0f / sx, iy = 1.0f / sy, iz = 1.0f / sz, iw = 1.0f / sw;
#pragma unroll
    for (int b = 0; b < B_; b++) {
        float4 o;
        o.x = v[b].x * ix; o.y = v[b].y * iy;
        o.z = v[b].z * iz; o.w = v[b].w * iw;
        *(float4*)(S + (long)b * NN + i4) = o;
        ushort4 ob;
        ob.x = f2bf(o.x); ob.y = f2bf(o.y); ob.z = f2bf(o.z); ob.w = f2bf(o.w);
        *(ushort4*)(Sc + (long)b * NN + i4) = ob;
    }
}

// ---------------------------------------------------------------------------
// P kernel: one block per row. |sigma| comes precomputed (asig) when the
// workspace is available; falls back to the in-block reduction otherwise.
// ---------------------------------------------------------------------------
__device__ __forceinline__ float block_reduce_sum(float v, float* red)
{
#pragma unroll
    for (int off = 32; off; off >>= 1) v += __shfl_down(v, off, 64);
    __syncthreads();
    if ((threadIdx.x & 63) == 0) red[threadIdx.x >> 6] = v;
    __syncthreads();
    return red[0] + red[1] + red[2] + red[3];
}

__global__ __launch_bounds__(256) void p_kernel(
    const float* __restrict__ x, const float* __restrict__ Wsig,
    const float* __restrict__ eps, float* __restrict__ P,
    const float* __restrict__ asig)
{
    __shared__ float red[4];
    const int bn = blockIdx.x;
    const int n = bn & (N_ - 1);
    const int tid = threadIdx.x;

    float a;
    if (asig) {
        a = asig[bn];
    } else {
        a = fabsf(block_reduce_sum(x[(long)bn * C_ + tid] * Wsig[tid], red));
    }

    const float* erow = eps + (long)bn * N_;
    const float4 e = *(const float4*)(erow + tid * 4);
    const int j0 = tid * 4;
    const float g0 = (float)abs(n - (j0 + 0)) + a * e.x;
    const float g1 = (float)abs(n - (j0 + 1)) + a * e.y;
    const float g2 = (float)abs(n - (j0 + 2)) + a * e.z;
    const float g3 = (float)abs(n - (j0 + 3)) + a * e.w;

    const float total = block_reduce_sum(g0 + g1 + g2 + g3, red);
    const float inv = 1.0f / total;

    float4 o;
    o.x = g0 * inv; o.y = g1 * inv; o.z = g2 * inv; o.w = g3 * inv;
    *(float4*)(P + (long)bn * N_ + j0) = o;
}

extern "C" void kernel_launch(void* const* d_in, const int* in_sizes, int n_in,
                              void* d_out, int out_size, void* d_ws, size_t ws_size,
                              hipStream_t stream)
{
    const float* x    = (const float*)d_in[0];
    const float* Wq   = (const float*)d_in[1];
    const float* Wk   = (const float*)d_in[2];
    const float* Wv   = (const float*)d_in[3];
    const float* Wsig = (const float*)d_in[4];
    const float* eps  = (const float*)d_in[5];
    float* out = (float*)d_out;

    const long ZN = (long)B_ * N_ * C_;   // 4,194,304
    const long PN = (long)B_ * N_ * N_;   // 16,777,216
    const long NC = (long)N_ * C_;
    const long NN = (long)N_ * N_;

    float* Zp = out;
    float* Pp = out + ZN;        // 64 MiB region, staged then overwritten last
    float* Sp = out + ZN + PN;

    // bf16 staging inside P region (lifetime-overlapped):
    //  [0,8M)B Qbf | [8,16M) Kbf | [16,24M) Vbf | [24,32M) xbf -> VbfT
    //  [32,64M) WbfT -> Scbf (raw bf16 scores, normalized in place by softmax)
    ushort_t* base = (ushort_t*)Pp;
    ushort_t* Qbf  = base;
    ushort_t* Kbf  = base + ZN;
    ushort_t* Vbf  = base + 2 * ZN;
    ushort_t* xbf  = base + 3 * ZN;   // dead after QKV gemm
    ushort_t* VbfT = base + 3 * ZN;   // born at transpose (after xbf dead)
    ushort_t* WbfT = base + 4 * ZN;   // dead after QKV gemm
    ushort_t* Scbf = base + 4 * ZN;   // born at scores gemm (after WbfT dead)

    // |sigma| per row via workspace (64 KB); fallback: in-block reduce
    float* asig = (ws_size >= (size_t)(B_ * N_) * sizeof(float))
                      ? (float*)d_ws : nullptr;

    const dim3 blk(256);

    // casts + sigma, one launch
    cast_fused<<<dim3(4096 + 192), blk, 0, stream>>>(
        x, xbf, Wq, Wk, Wv, WbfT, Wsig, asig);

    // Q|K|V = xbf @ WbfT^T  -> bf16, one batched launch (z strides both B and C)
    gemm_nt_bf16<1><<<dim3(2, 128, 3), blk, 0, stream>>>(
        xbf, WbfT, Qbf, B_ * N_, C_, C_, 0, 65536, ZN, 1.0f);

    // V -> V^T (bf16) for the Z gemm's B operand
    transpose_v_kernel<<<dim3(8, 32, 16), blk, 0, stream>>>(Vbf, VbfT);

    // scores = Qbf @ Kbf^T / 16 -> bf16 (32 MB instead of 64 MB fp32)
    gemm_nt_bf16<1><<<dim3(8, 8, 16), blk, 0, stream>>>(
        Qbf, Kbf, Scbf, N_, N_, C_, NC, NC, NN, 0.0625f);

    // softmax over batch axis; emits fp32 S (final output) + bf16 S in place
    softmax_batch<<<dim3(NN / 1024), blk, 0, stream>>>(Scbf, Sp);

    // Z = Sbf @ VbfT^T -> fp32
    gemm_nt_bf16<0><<<dim3(2, 8, 16), blk, 0, stream>>>(
        Scbf, VbfT, Zp, N_, C_, N_, NN, NC, NC, 1.0f);

    // P last (overwrites all bf16 staging)
    p_kernel<<<dim3(B_ * N_), blk, 0, stream>>>(x, Wsig, eps, Pp, asig);
}

// Round 2
// 280.536 us; speedup vs baseline: 1.0891x; 1.0261x over previous
//
#include <hip/hip_runtime.h>
#include <hip/hip_bf16.h>
#include <math.h>

#define B_ 16
#define N_ 1024
#define C_ 256

typedef unsigned short ushort_t;
typedef __attribute__((ext_vector_type(8))) short short8;   // 8 bf16 = 4 VGPRs
typedef __attribute__((ext_vector_type(4))) float f32x4;

static __device__ __forceinline__ ushort_t f2bf(float f) {
    __hip_bfloat16 h = __float2bfloat16(f);
    return *(ushort_t*)&h;
}

static __device__ __forceinline__ float bf2f(ushort_t u) {
    return __uint_as_float(((unsigned int)u) << 16);
}

// async global->LDS, 16B per lane; lds base must be wave-uniform (HW adds lane*16)
static __device__ __forceinline__ void async16(const ushort_t* g, ushort_t* l) {
    __builtin_amdgcn_global_load_lds(
        (const __attribute__((address_space(1))) unsigned int*)g,
        (__attribute__((address_space(3))) unsigned int*)l,
        16, 0, 0);
}

// ---------------------------------------------------------------------------
// C[M,N] = alpha * A[M,K] @ B[N,K]^T   (A,B bf16 row-major; C fp32 or bf16)
// 128x128 tile, BK=32, 8 waves (2x4), 16x16x32 MFMA, 4x2 tiles/wave.
// 512-thread blocks: Z gemm (1 block/CU) gets 2 waves/SIMD instead of 1;
// acc = 32 VGPR/thread keeps pressure low for multi-block residency elsewhere.
// 2-phase double-buffered LDS (stage next tile before compute, 1 barrier/step).
// SWZ: chunked XCD swizzle (lid%8 -> contiguous grid chunk per XCD) so blocks
// sharing A/B panels land on the same XCD L2. All grids are %8==0.
// Epilogue stages acc through first 16KB LDS -> coalesced float4/short8 stores.
// ---------------------------------------------------------------------------
template <int OUT_BF16, int SWZ>
__global__ __launch_bounds__(512) void gemm_nt_bf16(
    const ushort_t* __restrict__ A, const ushort_t* __restrict__ B,
    void* __restrict__ Cp, int M, int N, int K,
    long sA, long sB, long sC, float alpha)
{
    int bx = blockIdx.x, by = blockIdx.y, bz = blockIdx.z;
    if constexpr (SWZ) {
        const int gx = gridDim.x, gy = gridDim.y;
        const int nwg = gx * gy * (int)gridDim.z;
        const int lid = bx + gx * (by + gy * bz);
        const int cpx = nwg >> 3;
        const int s = (lid & 7) * cpx + (lid >> 3);
        bx = s % gx;
        const int t = s / gx;
        by = t % gy;
        bz = t / gy;
    }
    A += (long)bz * sA;
    B += (long)bz * sB;

    __shared__ ushort_t sh[2][2 * 128 * 32];   // double-buffered As|Bs (32 KB)
    float* shF = (float*)sh;                    // epilogue reuses first 16 KB

    const int tid  = threadIdx.x;
    const int wave = tid >> 6;          // 0..7
    const int lane = tid & 63;
    const int wm   = wave >> 2;         // row half of 128
    const int wn   = wave & 3;          // col quarter of 128
    const int row0 = by * 128;
    const int col0 = bx * 128;

    // ---- staging addresses (per wave: 1 group of 16 rows for A, 1 for B)
    const int r_grp = lane >> 2;        // 0..15 row within group
    const int c_chk = lane & 3;         // 0..3  16B chunk within 64B row
    const int swz   = c_chk ^ ((r_grp >> 1) & 3);   // swizzled source chunk

    const ushort_t* agp = A + (long)(row0 + wave * 16 + r_grp) * K + swz * 8;
    const ushort_t* bgp = B + (long)(col0 + wave * 16 + r_grp) * K + swz * 8;

    // ---- fragment read addressing
    const int lr16 = lane & 15;
    const int q16  = lane >> 4;                       // 0..3
    const int slot = (q16 ^ ((lr16 >> 1) & 3)) * 8;   // swizzled read slot

    f32x4 acc[4][2] = {};

    // prologue: stage k=0 into buffer 0
    {
        ushort_t* As = sh[0];
        ushort_t* Bs = sh[0] + 128 * 32;
        async16(agp, &As[wave * 512]);
        async16(bgp, &Bs[wave * 512]);
    }
    __syncthreads();   // drains vmcnt -> buf0 ready

    int p = 0;
    for (int k0 = 0; k0 < K; k0 += 32) {
        // issue next-tile stage first: overlaps with ds_read + MFMA below
        if (k0 + 32 < K) {
            ushort_t* As = sh[p ^ 1];
            ushort_t* Bs = sh[p ^ 1] + 128 * 32;
            async16(agp + k0 + 32, &As[wave * 512]);
            async16(bgp + k0 + 32, &Bs[wave * 512]);
        }

        const ushort_t* As = sh[p];
        const ushort_t* Bs = sh[p] + 128 * 32;
        short8 av[4], bv[2];
#pragma unroll
        for (int i = 0; i < 4; i++)
            av[i] = *(const short8*)&As[(wm * 64 + i * 16 + lr16) * 32 + slot];
#pragma unroll
        for (int j = 0; j < 2; j++)
            bv[j] = *(const short8*)&Bs[(wn * 32 + j * 16 + lr16) * 32 + slot];

#pragma unroll
        for (int i = 0; i < 4; i++)
#pragma unroll
            for (int j = 0; j < 2; j++)
                acc[i][j] = __builtin_amdgcn_mfma_f32_16x16x32_bf16(
                    av[i], bv[j], acc[i][j], 0, 0, 0);

        __syncthreads();   // next buf staged + this buf free for re-stage
        p ^= 1;
    }

    // ---- epilogue via LDS: 4 passes of 32 rows x 128 cols fp32 (16 KB)
    // acc C/D layout: col=lane&15, row=q16*4+reg
#pragma unroll
    for (int i = 0; i < 4; i++) {
#pragma unroll
        for (int j = 0; j < 2; j++) {
            const int rl = wm * 16 + q16 * 4;         // +r below
            const int cl = wn * 32 + j * 16 + lr16;
#pragma unroll
            for (int r = 0; r < 4; r++) {
                const int rr = rl + r;
                const int xr = ((rr >> 2) & 1) << 4;  // split quads across bank halves
                shF[rr * 128 + (cl ^ xr)] = alpha * acc[i][j][r];
            }
        }
        __syncthreads();

        if constexpr (OUT_BF16) {
            ushort_t* C = (ushort_t*)Cp + (long)bz * sC;
            const int idx = tid;                  // 0..511 short8-chunks
            const int rl = idx >> 4;              // 32 rows
            const int c8 = idx & 15;              // 16 chunks of 8 elems
            const int xr4 = ((rl >> 2) & 1) << 2; // float4-index XOR
            const int gr = row0 + (rl >> 4) * 64 + i * 16 + (rl & 15);
            const float4 a = ((const float4*)(shF + rl * 128))[(c8 * 2) ^ xr4];
            const float4 b = ((const float4*)(shF + rl * 128))[(c8 * 2 + 1) ^ xr4];
            short8 pk;
            pk[0] = (short)f2bf(a.x); pk[1] = (short)f2bf(a.y);
            pk[2] = (short)f2bf(a.z); pk[3] = (short)f2bf(a.w);
            pk[4] = (short)f2bf(b.x); pk[5] = (short)f2bf(b.y);
            pk[6] = (short)f2bf(b.z); pk[7] = (short)f2bf(b.w);
            *(short8*)(C + (long)gr * N + col0 + c8 * 8) = pk;
        } else {
            float* C = (float*)Cp + (long)bz * sC;
#pragma unroll
            for (int v = 0; v < 2; v++) {
                const int idx = v * 512 + tid;        // 0..1023 float4-chunks
                const int rl = idx >> 5;              // 32 rows
                const int c4 = idx & 31;
                const int xr4 = ((rl >> 2) & 1) << 2;
                const int gr = row0 + (rl >> 4) * 64 + i * 16 + (rl & 15);
                const float4 val = ((const float4*)(shF + rl * 128))[c4 ^ xr4];
                *(float4*)(C + (long)gr * N + col0 + c4 * 4) = val;
            }
        }
        __syncthreads();
    }
}

// ---------------------------------------------------------------------------
// Fused cast kernel, one launch:
//   blocks [0,4096): x fp32 -> bf16 (x4 vectorized) + per-row sigma = x . Wsig
//                    (one wave = one row; shuffle reduce; |sigma| -> asig)
//   blocks [4096,4288): W[256,256] fp32 (q/k/v) -> WbfT bf16 transposed
// ---------------------------------------------------------------------------
__global__ __launch_bounds__(256) void cast_fused(
    const float* __restrict__ x, ushort_t* __restrict__ xbf,
    const float* __restrict__ Wq, const float* __restrict__ Wk,
    const float* __restrict__ Wv, ushort_t* __restrict__ WbfT,
    const float* __restrict__ Wsig, float* __restrict__ asig)
{
    __shared__ float t[32][33];
    const int blk = blockIdx.x;
    if (blk < 4096) {
        const long i = ((long)blk * 256 + threadIdx.x) * 4;
        const float4 v = *(const float4*)(x + i);
        ushort4 o;
        o.x = f2bf(v.x); o.y = f2bf(v.y); o.z = f2bf(v.z); o.w = f2bf(v.w);
        *(ushort4*)(xbf + i) = o;
        if (asig) {
            const int lane = threadIdx.x & 63;
            const float4 w = *(const float4*)(Wsig + lane * 4);
            float d = v.x * w.x + v.y * w.y + v.z * w.z + v.w * w.w;
#pragma unroll
            for (int off = 32; off; off >>= 1) d += __shfl_down(d, off, 64);
            if (lane == 0) asig[blk * 4 + (threadIdx.x >> 6)] = fabsf(d);
        }
    } else {
        const int m = blk - 4096;                 // 0..191
        const float* W = ((m >> 6) == 0) ? Wq : ((m >> 6) == 1) ? Wk : Wv;
        const int rem = m & 63;
        const int n0 = (rem & 7) * 32, k0 = (rem >> 3) * 32;
        const int tx = threadIdx.x & 31, ty = threadIdx.x >> 5;   // (32,8)
#pragma unroll
        for (int j = 0; j < 4; j++)
            t[ty + j * 8][tx] = W[(long)(k0 + ty + j * 8) * 256 + n0 + tx];
        __syncthreads();
        ushort_t* o = WbfT + (long)(m >> 6) * 65536;
#pragma unroll
        for (int j = 0; j < 4; j++)
            o[(long)(n0 + ty + j * 8) * 256 + k0 + tx] = f2bf(t[tx][ty + j * 8]);
    }
}

// ---------------------------------------------------------------------------
// Vbf[b][1024,256] -> VbfT[b][256,1024] (bf16 LDS tile transpose)
// ---------------------------------------------------------------------------
__global__ __launch_bounds__(256) void transpose_v_kernel(
    const ushort_t* __restrict__ V, ushort_t* __restrict__ VT)
{
    __shared__ ushort_t t[32][33];
    const long NC = (long)N_ * C_;
    const ushort_t* Vb = V + (long)blockIdx.z * NC;
    ushort_t* Tb = VT + (long)blockIdx.z * NC;
    const int n0 = blockIdx.x * 32, m0 = blockIdx.y * 32;
    const int tx = threadIdx.x & 31, ty = threadIdx.x >> 5;
#pragma unroll
    for (int j = 0; j < 4; j++)
        t[ty + j * 8][tx] = Vb[(long)(m0 + ty + j * 8) * C_ + n0 + tx];
    __syncthreads();
#pragma unroll
    for (int j = 0; j < 4; j++)
        Tb[(long)(n0 + ty + j * 8) * N_ + m0 + tx] = t[tx][ty + j * 8];
}

// ---------------------------------------------------------------------------
// Softmax over batch axis (16 slices, stride N*N), 4 cells per thread.
// Reads bf16 raw scores, writes fp32 S (final output) + normalized bf16 back
// IN PLACE over the raw scores (each cell read+written by the same thread).
// ---------------------------------------------------------------------------
__global__ __launch_bounds__(256) void softmax_batch(
    ushort_t* __restrict__ Sc, float* __restrict__ S)
{
    const long NN = (long)N_ * N_;
    const long i4 = ((long)blockIdx.x * 256 + threadIdx.x) * 4;

    float4 v[B_];
    float mx = -INFINITY, my = -INFINITY, mz = -INFINITY, mw = -INFINITY;
#pragma unroll
    for (int b = 0; b < B_; b++) {
        const ushort4 u = *(const ushort4*)(Sc + (long)b * NN + i4);
        v[b].x = bf2f(u.x); v[b].y = bf2f(u.y);
        v[b].z = bf2f(u.z); v[b].w = bf2f(u.w);
        mx = fmaxf(mx, v[b].x); my = fmaxf(my, v[b].y);
        mz = fmaxf(mz, v[b].z); mw = fmaxf(mw, v[b].w);
    }
    float sx = 0.f, sy = 0.f, sz = 0.f, sw = 0.f;
#pragma unroll
    for (int b = 0; b < B_; b++) {
        v[b].x = __expf(v[b].x - mx); sx += v[b].x;
        v[b].y = __expf(v[b].y - my); sy += v[b].y;
        v[b].z = __expf(v[b].z - mz); sz += v[b].z;
        v[b].w = __expf(v[b].w - mw); sw += v[b].w;
    }
    const float ix = 1.0f / sx, iy = 1.0f / sy, iz = 1.0f / sz, iw = 1.0f / sw;
#pragma unroll
    for (int b = 0; b < B_; b++) {
        float4 o;
        o.x = v[b].x * ix; o.y = v[b].y * iy;
        o.z = v[b].z * iz; o.w = v[b].w * iw;
        *(float4*)(S + (long)b * NN + i4) = o;
        ushort4 ob;
        ob.x = f2bf(o.x); ob.y = f2bf(o.y); ob.z = f2bf(o.z); ob.w = f2bf(o.w);
        *(ushort4*)(Sc + (long)b * NN + i4) = ob;
    }
}

// ---------------------------------------------------------------------------
// P kernel: one WAVE per row (4 rows/block) — no LDS, no barriers, pure
// shuffle butterfly reductions. |sigma| precomputed (asig) when workspace
// available; fallback recomputes the dot in-wave.
// ---------------------------------------------------------------------------
__global__ __launch_bounds__(256) void p_kernel(
    const float* __restrict__ x, const float* __restrict__ Wsig,
    const float* __restrict__ eps, float* __restrict__ P,
    const float* __restrict__ asig)
{
    const int row  = blockIdx.x * 4 + (threadIdx.x >> 6);
    const int lane = threadIdx.x & 63;
    const int n = row & (N_ - 1);

    float a;
    if (asig) {
        a = asig[row];
    } else {
        const float4 xv = *(const float4*)(x + (long)row * C_ + lane * 4);
        const float4 wv = *(const float4*)(Wsig + lane * 4);
        float d = xv.x * wv.x + xv.y * wv.y + xv.z * wv.z + xv.w * wv.w;
#pragma unroll
        for (int off = 32; off; off >>= 1) d += __shfl_xor(d, off, 64);
        a = fabsf(d);
    }

    const float4* erow = (const float4*)(eps + (long)row * N_);
    float4 e[4], g[4];
    float sum = 0.f;
#pragma unroll
    for (int k = 0; k < 4; k++) {
        e[k] = erow[k * 64 + lane];
        const int j0 = (k * 64 + lane) * 4;
        g[k].x = (float)abs(n - (j0 + 0)) + a * e[k].x;
        g[k].y = (float)abs(n - (j0 + 1)) + a * e[k].y;
        g[k].z = (float)abs(n - (j0 + 2)) + a * e[k].z;
        g[k].w = (float)abs(n - (j0 + 3)) + a * e[k].w;
        sum += g[k].x + g[k].y + g[k].z + g[k].w;
    }
#pragma unroll
    for (int off = 32; off; off >>= 1) sum += __shfl_xor(sum, off, 64);
    const float inv = 1.0f / sum;

    float4* prow = (float4*)(P + (long)row * N_);
#pragma unroll
    for (int k = 0; k < 4; k++) {
        float4 o;
        o.x = g[k].x * inv; o.y = g[k].y * inv;
        o.z = g[k].z * inv; o.w = g[k].w * inv;
        prow[k * 64 + lane] = o;
    }
}

extern "C" void kernel_launch(void* const* d_in, const int* in_sizes, int n_in,
                              void* d_out, int out_size, void* d_ws, size_t ws_size,
                              hipStream_t stream)
{
    const float* x    = (const float*)d_in[0];
    const float* Wq   = (const float*)d_in[1];
    const float* Wk   = (const float*)d_in[2];
    const float* Wv   = (const float*)d_in[3];
    const float* Wsig = (const float*)d_in[4];
    const float* eps  = (const float*)d_in[5];
    float* out = (float*)d_out;

    const long ZN = (long)B_ * N_ * C_;   // 4,194,304
    const long PN = (long)B_ * N_ * N_;   // 16,777,216
    const long NC = (long)N_ * C_;
    const long NN = (long)N_ * N_;

    float* Zp = out;
    float* Pp = out + ZN;        // 64 MiB region, staged then overwritten last
    float* Sp = out + ZN + PN;

    // bf16 staging inside P region (lifetime-overlapped):
    //  [0,8M)B Qbf | [8,16M) Kbf | [16,24M) Vbf | [24,32M) xbf -> VbfT
    //  [32,64M) WbfT -> Scbf (raw bf16 scores, normalized in place by softmax)
    ushort_t* base = (ushort_t*)Pp;
    ushort_t* Qbf  = base;
    ushort_t* Kbf  = base + ZN;
    ushort_t* Vbf  = base + 2 * ZN;
    ushort_t* xbf  = base + 3 * ZN;   // dead after QKV gemm
    ushort_t* VbfT = base + 3 * ZN;   // born at transpose (after xbf dead)
    ushort_t* WbfT = base + 4 * ZN;   // dead after QKV gemm
    ushort_t* Scbf = base + 4 * ZN;   // born at scores gemm (after WbfT dead)

    // |sigma| per row via workspace (64 KB); fallback: in-wave reduce
    float* asig = (ws_size >= (size_t)(B_ * N_) * sizeof(float))
                      ? (float*)d_ws : nullptr;

    const dim3 blk(256);
    const dim3 blk512(512);

    // casts + sigma, one launch
    cast_fused<<<dim3(4096 + 192), blk, 0, stream>>>(
        x, xbf, Wq, Wk, Wv, WbfT, Wsig, asig);

    // Q|K|V = xbf @ WbfT^T  -> bf16, one batched launch (z strides both B and C)
    gemm_nt_bf16<1, 1><<<dim3(2, 128, 3), blk512, 0, stream>>>(
        xbf, WbfT, Qbf, B_ * N_, C_, C_, 0, 65536, ZN, 1.0f);

    // V -> V^T (bf16) for the Z gemm's B operand
    transpose_v_kernel<<<dim3(8, 32, 16), blk, 0, stream>>>(Vbf, VbfT);

    // scores = Qbf @ Kbf^T / 16 -> bf16 (chunked XCD swizzle: 2 batches/XCD)
    gemm_nt_bf16<1, 1><<<dim3(8, 8, 16), blk512, 0, stream>>>(
        Qbf, Kbf, Scbf, N_, N_, C_, NC, NC, NN, 0.0625f);

    // softmax over batch axis; emits fp32 S (final output) + bf16 S in place
    softmax_batch<<<dim3(NN / 1024), blk, 0, stream>>>(Scbf, Sp);

    // Z = Sbf @ VbfT^T -> fp32
    gemm_nt_bf16<0, 1><<<dim3(2, 8, 16), blk512, 0, stream>>>(
        Scbf, VbfT, Zp, N_, C_, N_, NN, NC, NC, 1.0f);

    // P last (overwrites all bf16 staging)
    p_kernel<<<dim3((B_ * N_) / 4), blk, 0, stream>>>(x, Wsig, eps, Pp, asig);
}